// Round 21
// baseline (32261.664 us; speedup 1.0000x reference)
//
#include <hip/hip_runtime.h>
#include <cstdint>
#include <cstddef>

// Problem constants
#define LN_L 4      // layers
#define NB   8      // batch images
#define NPH  37
#define NPW  37
#define NP   1369   // patches = 37*37
#define ND   1024   // feature dim
#define NH   518
#define NW   518
#define NR   3      // r in {1,3,5}
#define NNB  7      // B-1 neighbors
#define NTOP 3      // k1-k0
#define PCHK 8
#define LBP  (LN_L * NB * NP)   // 43808

// Output layout (all float32, concatenated flat in return order)
static constexpr size_t OFF_FINAL = 0;                                        // (8,)
static constexpr size_t OFF_PIX   = 8;                                        // (8,518,518)
static constexpr size_t OFF_MINI  = OFF_PIX + (size_t)NB * NH * NW;           // (8,4,3,7,1369)
static constexpr size_t OFF_MAXI  = OFF_MINI + (size_t)NB * LN_L * NR * NNB * NP; // (8,)
static constexpr size_t OFF_TKI   = OFF_MAXI + NB;                            // (8,4,3,3,1369)
static constexpr size_t OFF_TKS   = OFF_TKI + (size_t)NB * LN_L * NR * NTOP * NP; // (8,4,3,3,1369)

// ---------------- utility ----------------

__device__ __forceinline__ unsigned long long shflxor_u64(unsigned long long v, int m) {
    int lo = __shfl_xor((int)(unsigned)v, m);
    int hi = __shfl_xor((int)(unsigned)(v >> 32), m);
    return ((unsigned long long)(unsigned)hi << 32) | (unsigned)lo;
}

__device__ __forceinline__ double shfl_xor_f64(double v, int m) {
    long long x = __double_as_longlong(v);
    int lo = (int)(x & 0xffffffffLL);
    int hi = (int)(x >> 32);
    lo = __shfl_xor(lo, m);
    hi = __shfl_xor(hi, m);
    return __longlong_as_double(((long long)hi << 32) | (unsigned long long)(unsigned)lo);
}

// numpy pairwise_sum over 1024 contiguous f32 mapped to one wave (bit-exact:
// 8 leaves of 128 with 8 stride-8 accumulators, halving combine trees).
__device__ __forceinline__ float np_pairwise_wave(float r) {
    r = __fadd_rn(r, __shfl_xor(r, 1));
    r = __fadd_rn(r, __shfl_xor(r, 2));
    r = __fadd_rn(r, __shfl_xor(r, 4));
    r = __fadd_rn(r, __shfl_xor(r, 8));
    r = __fadd_rn(r, __shfl_xor(r, 16));
    r = __fadd_rn(r, __shfl_xor(r, 32));
    return r;
}

// ---------------- stage 0: np-exact LN stats (np.mean / np.var pairwise, f32) ----------------
// Stores sq = f32 sqrt(f32(v + 1e-5)); fn computed later as f32( f32(x-m) / sq )
// (f32 DIVISION -- the best-performing LN variant in the f64-key class).

__global__ __launch_bounds__(256) void stats_np_kernel(const float* __restrict__ feat,
                                                       float* __restrict__ m32,
                                                       float* __restrict__ sq32) {
    int row = blockIdx.x * 4 + (threadIdx.x >> 6);
    if (row >= LBP) return;
    int lane = threadIdx.x & 63;
    const float* x = feat + (size_t)row * ND;
    const int base = 128 * (lane >> 3) + (lane & 7);
    float xv[16];
    #pragma unroll
    for (int k = 0; k < 16; ++k) xv[k] = x[base + 8 * k];
    float r = xv[0];
    #pragma unroll
    for (int k = 1; k < 16; ++k) r = __fadd_rn(r, xv[k]);
    float m = __fdiv_rn(np_pairwise_wave(r), 1024.0f);
    float d0 = __fsub_rn(xv[0], m);
    float s = __fmul_rn(d0, d0);
    #pragma unroll
    for (int k = 1; k < 16; ++k) {
        float dk = __fsub_rn(xv[k], m);
        s = __fadd_rn(s, __fmul_rn(dk, dk));
    }
    float v = __fdiv_rn(np_pairwise_wave(s), 1024.0f);
    if (lane == 0) {
        m32[row] = m;
        sq32[row] = __fsqrt_rn(__fadd_rn(v, 1e-5f));
    }
}

// ---------------- stage 1: rf = raster-order shifted-slice f32 accumulation, then /r^2 ----------------
// fn = f32( f32(x - m) / sq ); r==1 -> rf = fn exactly.

__global__ __launch_bounds__(256) void pool_np_kernel(const float* __restrict__ feat,
                                                      const float* __restrict__ m32,
                                                      const float* __restrict__ sq32,
                                                      float* __restrict__ rf,
                                                      int r) {
    int row = blockIdx.x;   // (l*NB+b)*NP + p
    int p   = row % NP;
    int lb  = row / NP;
    int ph  = p / NPW, pw = p % NPW;
    int hr  = r >> 1;
    const int t = threadIdx.x;
    float a0 = 0.f, a1 = 0.f, a2 = 0.f, a3 = 0.f;
    for (int dh = -hr; dh <= hr; ++dh) {         // raster order over window
        int hh = ph + dh;
        if ((unsigned)hh >= NPH) continue;        // padded zeros: exact no-op
        for (int dw = -hr; dw <= hr; ++dw) {
            int wp = pw + dw;
            if ((unsigned)wp >= NPW) continue;
            int rq = lb * NP + hh * NPW + wp;
            float m = m32[rq], sq = sq32[rq];
            float4 v = *(const float4*)&feat[(size_t)rq * ND + 4 * t];
            a0 = __fadd_rn(a0, __fdiv_rn(__fsub_rn(v.x, m), sq));
            a1 = __fadd_rn(a1, __fdiv_rn(__fsub_rn(v.y, m), sq));
            a2 = __fadd_rn(a2, __fdiv_rn(__fsub_rn(v.z, m), sq));
            a3 = __fadd_rn(a3, __fdiv_rn(__fsub_rn(v.w, m), sq));
        }
    }
    float4 o;
    if (r == 1) { o.x = a0; o.y = a1; o.z = a2; o.w = a3; }
    else {
        float rd = (float)(r * r);
        o.x = __fdiv_rn(a0, rd); o.y = __fdiv_rn(a1, rd);
        o.z = __fdiv_rn(a2, rd); o.w = __fdiv_rn(a3, rd);
    }
    *(float4*)&rf[(size_t)row * ND + 4 * t] = o;
}

// ---------------- x2 = np.sum(f*f, -1): pairwise over f32 squares ----------------

__global__ __launch_bounds__(256) void x2_np_kernel(const float* __restrict__ rf,
                                                    float* __restrict__ x2r) {
    int row = blockIdx.x * 4 + (threadIdx.x >> 6);
    if (row >= LBP) return;
    int lane = threadIdx.x & 63;
    const float* x = rf + (size_t)row * ND;
    const int base = 128 * (lane >> 3) + (lane & 7);
    float v0 = x[base];
    float s = __fmul_rn(v0, v0);
    #pragma unroll
    for (int k = 1; k < 16; ++k) {
        float vk = x[base + 8 * k];
        s = __fadd_rn(s, __fmul_rn(vk, vk));
    }
    float total = np_pairwise_wave(s);
    if (lane == 0) x2r[row] = total;
}

// ---------------- gram: per-entry sequential ascending FMA chain ----------------

__global__ __launch_bounds__(256) void gram_fma32_kernel(const float* __restrict__ rf,
                                                         float* __restrict__ Gbuf,
                                                         int l, int bc0, int bc1) {
    __shared__ float As[16][64];
    __shared__ float Bs[16][64];
    const int pi = blockIdx.z;
    const int bc = pi ? bc1 : bc0;
    const int b = bc >> 3, c = bc & 7;
    float* G = Gbuf + (size_t)pi * NP * NP;
    const int p0 = blockIdx.y * 64;
    const int q0 = blockIdx.x * 64;
    const int t = threadIdx.x;
    const int lrow = t >> 2;         // 0..63
    const int lk4  = (t & 3) << 2;   // 0,4,8,12
    const int tx = t & 15, ty = t >> 4;

    const int pa = p0 + lrow, qa = q0 + lrow;
    const bool pok = pa < NP, qok = qa < NP;
    const float* rowA = rf + ((size_t)(l * NB + b) * NP + (pok ? pa : 0)) * ND;
    const float* rowB = rf + ((size_t)(l * NB + c) * NP + (qok ? qa : 0)) * ND;

    float acc[4][4];
    #pragma unroll
    for (int i = 0; i < 4; ++i)
        #pragma unroll
        for (int j = 0; j < 4; ++j) acc[i][j] = 0.f;

    for (int k0 = 0; k0 < ND; k0 += 16) {
        float4 va, vb;
        if (pok) va = *(const float4*)&rowA[k0 + lk4];
        else { va.x = va.y = va.z = va.w = 0.f; }
        if (qok) vb = *(const float4*)&rowB[k0 + lk4];
        else { vb.x = vb.y = vb.z = vb.w = 0.f; }
        As[lk4 + 0][lrow] = va.x; As[lk4 + 1][lrow] = va.y;
        As[lk4 + 2][lrow] = va.z; As[lk4 + 3][lrow] = va.w;
        Bs[lk4 + 0][lrow] = vb.x; Bs[lk4 + 1][lrow] = vb.y;
        Bs[lk4 + 2][lrow] = vb.z; Bs[lk4 + 3][lrow] = vb.w;
        __syncthreads();
        #pragma unroll
        for (int kk = 0; kk < 16; ++kk) {       // strictly ascending k
            float ar[4], br[4];
            #pragma unroll
            for (int i = 0; i < 4; ++i) ar[i] = As[kk][ty * 4 + i];
            #pragma unroll
            for (int j = 0; j < 4; ++j) br[j] = Bs[kk][tx * 4 + j];
            #pragma unroll
            for (int i = 0; i < 4; ++i)
                #pragma unroll
                for (int j = 0; j < 4; ++j)
                    acc[i][j] = __fmaf_rn(ar[i], br[j], acc[i][j]);
        }
        __syncthreads();
    }
    #pragma unroll
    for (int i = 0; i < 4; ++i) {
        int p = p0 + ty * 4 + i;
        if (p < NP) {
            #pragma unroll
            for (int j = 0; j < 4; ++j) {
                int q = q0 + tx * 4 + j;
                if (q < NP) G[(size_t)p * NP + q] = acc[i][j];
            }
        }
    }
}

// ---------------- decision key: f32 d^2 + first-index tiebreak ----------------

__device__ __forceinline__ unsigned long long d2_key(float x2a, float x2b_, float g, unsigned idx) {
    float d2 = __fsub_rn(__fadd_rn(x2a, x2b_), __fmul_rn(2.0f, g));
    return ((unsigned long long)__float_as_uint(d2) << 32) | idx;   // d2 > 0 always
}

__global__ __launch_bounds__(256) void rowminF_kernel(const float* __restrict__ G,
                                                      const float* __restrict__ x2r,
                                                      float* __restrict__ md2,
                                                      int* __restrict__ mi,
                                                      int ri, int l, int bc0, int bc1) {
    const int pi = blockIdx.y;
    const int bc = pi ? bc1 : bc0;
    const int b = bc >> 3, c = bc & 7;
    const int p = blockIdx.x;
    const float* row = G + (size_t)pi * NP * NP + (size_t)p * NP;
    const float* x2b = x2r + (size_t)(l * NB + b) * NP;
    const float* x2c = x2r + (size_t)(l * NB + c) * NP;
    const float x2p = x2b[p];
    const int t = threadIdx.x;
    unsigned long long best = ~0ull;
    for (int q = t; q < NP; q += 256) {
        unsigned long long k = d2_key(x2p, x2c[q], row[q], (unsigned)q);
        if (k < best) best = k;
    }
    #pragma unroll
    for (int m = 1; m < 64; m <<= 1) {
        unsigned long long o = shflxor_u64(best, m);
        if (o < best) best = o;
    }
    __shared__ unsigned long long sm[4];
    if ((t & 63) == 0) sm[t >> 6] = best;
    __syncthreads();
    if (t == 0) {
        #pragma unroll
        for (int w = 1; w < 4; ++w)
            if (sm[w] < best) best = sm[w];
        int cc = c - (c > b ? 1 : 0);
        size_t o = ((((size_t)ri * LN_L + l) * NB + b) * NP + p) * NNB + cc;
        md2[o] = __uint_as_float((unsigned)(best >> 32));
        mi[o]  = (int)(unsigned)(best & 0xffffffffu);
    }
}

__global__ __launch_bounds__(256) void colminpF_kernel(const float* __restrict__ G,
                                                       const float* __restrict__ x2r,
                                                       unsigned long long* __restrict__ pvk,
                                                       int l, int bc0, int bc1) {
    const int pi = blockIdx.z;
    const int bc = pi ? bc1 : bc0;
    const int b = bc >> 3, c = bc & 7;
    const int q = blockIdx.x * 256 + threadIdx.x;
    const int ch = blockIdx.y;
    if (q >= NP) return;
    const float* x2b = x2r + (size_t)(l * NB + b) * NP;
    const float  x2q = x2r[(size_t)(l * NB + c) * NP + q];
    const float* Gp = G + (size_t)pi * NP * NP;
    const int p0 = ch * 172, p1 = p0 + 172 < NP ? p0 + 172 : NP;
    unsigned long long best = ~0ull;
    for (int p = p0; p < p1; ++p) {
        unsigned long long k = d2_key(x2q, x2b[p], Gp[(size_t)p * NP + q], (unsigned)p);
        if (k < best) best = k;
    }
    pvk[((size_t)pi * PCHK + ch) * NP + q] = best;
}

__global__ __launch_bounds__(256) void colminfF_kernel(const unsigned long long* __restrict__ pvk,
                                                       float* __restrict__ md2,
                                                       int* __restrict__ mi,
                                                       int ri, int l, int bc0, int bc1) {
    const int pi = blockIdx.y;
    const int bc = pi ? bc1 : bc0;
    const int b = bc >> 3, c = bc & 7;
    const int q = blockIdx.x * 256 + threadIdx.x;
    if (q >= NP) return;
    unsigned long long best = ~0ull;
    for (int ch = 0; ch < PCHK; ++ch) {
        unsigned long long k = pvk[((size_t)pi * PCHK + ch) * NP + q];
        if (k < best) best = k;
    }
    int cc = b - (b > c ? 1 : 0);
    size_t o = ((((size_t)ri * LN_L + l) * NB + c) * NP + q) * NNB + cc;
    md2[o] = __uint_as_float((unsigned)(best >> 32));
    mi[o]  = (int)(unsigned)(best & 0xffffffffu);
}

// ---------------- select: sort by (f32 d^2, first-index); d and scores in f64 ----------------

__global__ __launch_bounds__(256) void selectF_kernel(const float* __restrict__ md2,
                                                      const int* __restrict__ mi,
                                                      float* __restrict__ out,
                                                      double* __restrict__ scores_acc,
                                                      float* __restrict__ scores_buf) {
    int idx = blockIdx.x * 256 + threadIdx.x;
    if (idx >= NB * NP) return;
    int b = idx / NP, p = idx % NP;
    double racc = 0.0;
    for (int ri = 0; ri < NR; ++ri) {
        double lacc = 0.0;
        for (int l = 0; l < LN_L; ++l) {
            size_t base = ((((size_t)ri * LN_L + l) * NB + b) * NP + p) * NNB;
            size_t bm = OFF_MINI + ((((size_t)b * LN_L + l) * NR + ri) * NNB) * NP + p;
            unsigned long long keys[NNB];
            #pragma unroll
            for (int j = 0; j < NNB; ++j) {
                float v = md2[base + j];
                out[bm + (size_t)j * NP] = (float)mi[base + j];
                keys[j] = ((unsigned long long)__float_as_uint(v) << 32) | (unsigned)j;
            }
            #pragma unroll
            for (int i2 = 0; i2 < NNB - 1; ++i2)
                #pragma unroll
                for (int j2 = 0; j2 < NNB - 1 - i2; ++j2)
                    if (keys[j2] > keys[j2 + 1]) {
                        unsigned long long tmp = keys[j2];
                        keys[j2] = keys[j2 + 1];
                        keys[j2 + 1] = tmp;
                    }
            size_t bt = OFF_TKI + ((((size_t)b * LN_L + l) * NR + ri) * NTOP) * NP + p;
            size_t bs = OFF_TKS + ((((size_t)b * LN_L + l) * NR + ri) * NTOP) * NP + p;
            double v0 = sqrt(fmax((double)__uint_as_float((unsigned)(keys[0] >> 32)), 1e-12));
            double v1 = sqrt(fmax((double)__uint_as_float((unsigned)(keys[1] >> 32)), 1e-12));
            double v2 = sqrt(fmax((double)__uint_as_float((unsigned)(keys[2] >> 32)), 1e-12));
            out[bt + 0 * NP] = (float)(unsigned)(keys[0] & 0xffffffffu);
            out[bt + 1 * NP] = (float)(unsigned)(keys[1] & 0xffffffffu);
            out[bt + 2 * NP] = (float)(unsigned)(keys[2] & 0xffffffffu);
            out[bs + 0 * NP] = (float)v0;
            out[bs + 1 * NP] = (float)v1;
            out[bs + 2 * NP] = (float)v2;
            lacc += ((v0 + v1) + v2) / 3.0;
        }
        racc += lacc / 4.0;
    }
    double sc = racc / 3.0;
    scores_acc[idx] = sc;
    scores_buf[idx] = (float)sc;
}

// ---------------- final scores: f64 argmax (first index), bilinear upsample ----------------

__global__ __launch_bounds__(256) void score_max64_kernel(const double* __restrict__ scores_acc,
                                                          float* __restrict__ out) {
    int b = blockIdx.x;
    int t = threadIdx.x;
    double bv = -1e300; int bi = NP;
    for (int p = t; p < NP; p += 256) {
        double s = scores_acc[b * NP + p];
        if (s > bv || (s == bv && p < bi)) { bv = s; bi = p; }
    }
    #pragma unroll
    for (int m = 1; m < 64; m <<= 1) {
        double ov = shfl_xor_f64(bv, m);
        int    oi = __shfl_xor(bi, m);
        if (ov > bv || (ov == bv && oi < bi)) { bv = ov; bi = oi; }
    }
    __shared__ double sv[4];
    __shared__ int    si[4];
    if ((t & 63) == 0) { sv[t >> 6] = bv; si[t >> 6] = bi; }
    __syncthreads();
    if (t == 0) {
        #pragma unroll
        for (int w = 1; w < 4; ++w)
            if (sv[w] > bv || (sv[w] == bv && si[w] < bi)) { bv = sv[w]; bi = si[w]; }
        out[OFF_FINAL + b] = (float)bv;
        out[OFF_MAXI + b]  = (float)bi;
    }
}

__global__ __launch_bounds__(256) void upsample_kernel(const float* __restrict__ scores_buf,
                                                       float* __restrict__ out) {
    int bh = blockIdx.x;
    int b  = bh / NH, hh = bh % NH;
    double ph = (double)hh * 36.0 / 517.0;
    int i0 = (int)ph;
    double wh = ph - (double)i0;
    int i1 = (i0 + 1 > 36) ? 36 : i0 + 1;
    const float* pt = scores_buf + (size_t)b * NP;
    for (int w = threadIdx.x; w < NW; w += 256) {
        double pw_ = (double)w * 36.0 / 517.0;
        int j0 = (int)pw_;
        double ww = pw_ - (double)j0;
        int j1 = (j0 + 1 > 36) ? 36 : j0 + 1;
        float v00 = pt[i0 * NPW + j0], v01 = pt[i0 * NPW + j1];
        float v10 = pt[i1 * NPW + j0], v11 = pt[i1 * NPW + j1];
        float rr = (float)((1.0 - wh) * ((1.0 - ww) * v00 + ww * v01) +
                           wh * ((1.0 - ww) * v10 + ww * v11));
        out[OFF_PIX + (size_t)bh * NW + w] = rr;
    }
}

// ---------------- launch ----------------

extern "C" void kernel_launch(void* const* d_in, const int* in_sizes, int n_in,
                              void* d_out, int out_size, void* d_ws, size_t ws_size,
                              hipStream_t stream) {
    const float* feat = (const float*)d_in[0];
    float* out = (float*)d_out;
    char* ws = (char*)d_ws;
    (void)ws_size; (void)in_sizes; (void)n_in; (void)out_size;

    auto align256 = [](size_t x) { return (x + 255) & ~(size_t)255; };
    size_t o = 0;
    float* m32  = (float*)(ws + o);  o = align256(o + (size_t)LBP * sizeof(float));
    float* sq32 = (float*)(ws + o);  o = align256(o + (size_t)LBP * sizeof(float));
    float* rf   = (float*)(ws + o);  o = align256(o + (size_t)LBP * ND * sizeof(float)); // 134 MB
    float* x2r  = (float*)(ws + o);  o = align256(o + (size_t)LBP * sizeof(float));
    float* G    = (float*)(ws + o);  o = align256(o + (size_t)2 * NP * NP * sizeof(float)); // 15 MB
    float* md2  = (float*)(ws + o);  o = align256(o + (size_t)NR * LN_L * NB * NP * NNB * sizeof(float));
    int*   mi   = (int*)(ws + o);    o = align256(o + (size_t)NR * LN_L * NB * NP * NNB * sizeof(int));
    unsigned long long* pvk = (unsigned long long*)(ws + o);
    o = align256(o + (size_t)2 * PCHK * NP * sizeof(unsigned long long));
    double* scores_acc = (double*)(ws + o); o = align256(o + (size_t)NB * NP * sizeof(double));
    float*  scores_buf = (float*)(ws + o);  o = align256(o + (size_t)NB * NP * sizeof(float));

    stats_np_kernel<<<LBP / 4, 256, 0, stream>>>(feat, m32, sq32);

    // cross-pair list (b<c)
    int pb[28], pc[28], npair = 0;
    for (int b = 0; b < NB; ++b)
        for (int c = b + 1; c < NB; ++c) { pb[npair] = b; pc[npair] = c; ++npair; }

    const int rlist[NR] = {1, 3, 5};
    for (int ri = 0; ri < NR; ++ri) {
        pool_np_kernel<<<LBP, 256, 0, stream>>>(feat, m32, sq32, rf, rlist[ri]);
        x2_np_kernel<<<LBP / 4, 256, 0, stream>>>(rf, x2r);
        for (int l = 0; l < LN_L; ++l) {
            for (int c0 = 0; c0 < npair; c0 += 2) {
                int n = npair - c0 < 2 ? npair - c0 : 2;
                int i1 = c0 + (n > 1 ? 1 : 0);
                int e0 = pb[c0] * 8 + pc[c0];
                int e1 = pb[i1] * 8 + pc[i1];
                gram_fma32_kernel<<<dim3(22, 22, n), 256, 0, stream>>>(rf, G, l, e0, e1);
                rowminF_kernel<<<dim3(NP, n), 256, 0, stream>>>(G, x2r, md2, mi, ri, l, e0, e1);
                colminpF_kernel<<<dim3(6, PCHK, n), 256, 0, stream>>>(G, x2r, pvk, l, e0, e1);
                colminfF_kernel<<<dim3(6, n), 256, 0, stream>>>(pvk, md2, mi, ri, l, e0, e1);
            }
        }
    }

    selectF_kernel<<<(NB * NP + 255) / 256, 256, 0, stream>>>(md2, mi, out, scores_acc, scores_buf);
    score_max64_kernel<<<NB, 256, 0, stream>>>(scores_acc, out);
    upsample_kernel<<<NB * NH, 256, 0, stream>>>(scores_buf, out);
}